// Round 1
// baseline (595.992 us; speedup 1.0000x reference)
//
#include <hip/hip_runtime.h>

#define IN_DIM 128
#define OUT_DIM 64
#define EDGES_PER_BLOCK 4

// One wave (64 lanes) per edge. Lane o computes output element o:
//   out[e][o] = relu( sum_i W[idx[e]][o][i] * x[e][i] + b[idx[e]][o] )
// x is staged in LDS (512 B/edge) and read as broadcast (conflict-free).
// W rows are read as float4 (16B/lane, 16B-aligned: row stride 512 B).
__global__ __launch_bounds__(256) void msg_op_kernel(
    const float* __restrict__ x,      // [E, 128]
    const int*   __restrict__ idx,    // [E]
    const float* __restrict__ Wpool,  // [P, 64, 128]
    const float* __restrict__ bpool,  // [P, 64]
    float*       __restrict__ out,    // [E, 64]
    int E)
{
    __shared__ float xs[EDGES_PER_BLOCK][IN_DIM];
    const int wave = threadIdx.x >> 6;
    const int lane = threadIdx.x & 63;
    const int e = blockIdx.x * EDGES_PER_BLOCK + wave;

    if (e < E) {
        // stage x: each lane loads 2 contiguous floats (coalesced 8 B/lane)
        const float2 xv = *reinterpret_cast<const float2*>(
            &x[(size_t)e * IN_DIM + (size_t)lane * 2]);
        xs[wave][lane * 2]     = xv.x;
        xs[wave][lane * 2 + 1] = xv.y;
    }
    __syncthreads();
    if (e >= E) return;

    const int p = idx[e];
    const float* Wrow = Wpool + (size_t)p * (OUT_DIM * IN_DIM)
                              + (size_t)lane * IN_DIM;

    float acc = 0.f;
    #pragma unroll 8
    for (int i = 0; i < IN_DIM; i += 4) {
        const float4 w  = *reinterpret_cast<const float4*>(&Wrow[i]);
        const float4 xv = *reinterpret_cast<const float4*>(&xs[wave][i]);
        acc += w.x * xv.x;
        acc += w.y * xv.y;
        acc += w.z * xv.z;
        acc += w.w * xv.w;
    }

    acc += bpool[(size_t)p * OUT_DIM + lane];
    out[(size_t)e * OUT_DIM + lane] = fmaxf(acc, 0.f);
}

extern "C" void kernel_launch(void* const* d_in, const int* in_sizes, int n_in,
                              void* d_out, int out_size, void* d_ws, size_t ws_size,
                              hipStream_t stream) {
    const float* x    = (const float*)d_in[0];   // nodes_features_input [E,128,1]
    const int*   idx  = (const int*)d_in[1];     // edges_index [E]
    const float* W    = (const float*)d_in[2];   // edges_input_core [P,64,128]
    const float* b    = (const float*)d_in[3];   // edges_input_bias [P,64,1]
    float* out = (float*)d_out;                  // [E,64,1] fp32

    const int E = in_sizes[1];
    const int blocks = (E + EDGES_PER_BLOCK - 1) / EDGES_PER_BLOCK;
    msg_op_kernel<<<blocks, 256, 0, stream>>>(x, idx, W, b, out, E);
}

// Round 3
// 469.308 us; speedup vs baseline: 1.2699x; 1.2699x over previous
//
#include <hip/hip_runtime.h>

#define IN_DIM 128
#define OUT_DIM 64
#define MAXCHUNK 64

// ---- Phase 1: per-pool-entry linked lists (head[P], next[E]) ----

__global__ void init_head_kernel(int* __restrict__ head, int P) {
    int i = blockIdx.x * 256 + threadIdx.x;
    if (i < P) head[i] = -1;
}

__global__ void build_lists_kernel(const int* __restrict__ idx,
                                   int* __restrict__ head,
                                   int* __restrict__ nextp, int E) {
    int e = blockIdx.x * 256 + threadIdx.x;
    if (e < E) {
        int p = idx[e];
        int old = atomicExch(&head[p], e);
        nextp[e] = old;
    }
}

// ---- Phase 2: one block per pool entry p. Stage W[p] (32 KB) in LDS once,
// process every edge with idx==p (avg multiplicity E/P = 5) from LDS. ----
//
// LDS W layout: transposed float4 tiles Ws[i4][o] (i4 = i/4), padded to 65
// so compute reads (lane o reads Ws[i4][lane]) are contiguous 16B/lane ->
// conflict-free; staging writes are 4-way (free-ish, only 8 per wave).
__global__ __launch_bounds__(256) void gemv_pool_kernel(
    const float* __restrict__ x,      // [E,128]
    const float* __restrict__ Wpool,  // [P,64,128]
    const float* __restrict__ bpool,  // [P,64]
    float*       __restrict__ out,    // [E,64]
    const int*   __restrict__ head,
    const int*   __restrict__ nextp)
{
    __shared__ float4 Ws[32][OUT_DIM + 1];   // 33280 B
    __shared__ float  bs[OUT_DIM];
    __shared__ float  xs[4][IN_DIM];         // per-wave x staging
    __shared__ int    elist[MAXCHUNK];
    __shared__ int    ecount;
    __shared__ int    ecur;

    const int p = blockIdx.x;
    const int h = head[p];
    if (h < 0) return;                        // empty bucket, uniform exit

    const int wave = threadIdx.x >> 6;
    const int lane = threadIdx.x & 63;

    if (wave == 0) {
        bs[lane] = bpool[(size_t)p * OUT_DIM + lane];
        if (lane == 0) {
            // chase first chunk while waves 1-3 stage W
            int n = 0, c = h;
            while (c >= 0 && n < MAXCHUNK) { elist[n++] = c; c = nextp[c]; }
            ecount = n;
            ecur = c;
        }
    } else {
        const float4* Wg = reinterpret_cast<const float4*>(
            Wpool + (size_t)p * (OUT_DIM * IN_DIM));
        for (int q = threadIdx.x - 64; q < OUT_DIM * 32; q += 192) {
            int o = q >> 5, i4 = q & 31;      // Wg[q] = W[o][4*i4 .. 4*i4+3]
            Ws[i4][o] = Wg[q];
        }
    }
    __syncthreads();

    while (true) {
        const int n = ecount;
        for (int j = wave; j < n; j += 4) {
            const int e = elist[j];
            // stage x[e] into this wave's LDS row (coalesced 512 B)
            const float2 xv = reinterpret_cast<const float2*>(
                x + (size_t)e * IN_DIM)[lane];
            reinterpret_cast<float2*>(xs[wave])[lane] = xv;
            const float4* xrow = reinterpret_cast<const float4*>(xs[wave]);
            float ax = 0.f, ay = 0.f, az = 0.f, aw = 0.f;
            #pragma unroll 8
            for (int i4 = 0; i4 < 32; ++i4) {
                const float4 w  = Ws[i4][lane];
                const float4 xq = xrow[i4];   // broadcast read (same addr)
                ax += w.x * xq.x;
                ay += w.y * xq.y;
                az += w.z * xq.z;
                aw += w.w * xq.w;
            }
            const float acc = (ax + ay) + (az + aw) + bs[lane];
            out[(size_t)e * OUT_DIM + lane] = fmaxf(acc, 0.f);
        }
        if (n < MAXCHUNK) break;              // chain exhausted (uniform)
        __syncthreads();                      // elist fully consumed
        if (threadIdx.x == 0) {               // refill next chunk
            int nn = 0, c = ecur;
            while (c >= 0 && nn < MAXCHUNK) { elist[nn++] = c; c = nextp[c]; }
            ecount = nn;
            ecur = c;
        }
        __syncthreads();
    }
}

extern "C" void kernel_launch(void* const* d_in, const int* in_sizes, int n_in,
                              void* d_out, int out_size, void* d_ws, size_t ws_size,
                              hipStream_t stream) {
    const float* x    = (const float*)d_in[0];   // [E,128,1]
    const int*   idx  = (const int*)d_in[1];     // [E]
    const float* W    = (const float*)d_in[2];   // [P,64,128]
    const float* b    = (const float*)d_in[3];   // [P,64,1]
    float* out = (float*)d_out;                  // [E,64,1] fp32

    const int E = in_sizes[1];
    const int P = in_sizes[2] / (OUT_DIM * IN_DIM);

    int* head  = (int*)d_ws;                     // P ints
    int* nextp = head + P;                       // E ints

    init_head_kernel<<<(P + 255) / 256, 256, 0, stream>>>(head, P);
    build_lists_kernel<<<(E + 255) / 256, 256, 0, stream>>>(idx, head, nextp, E);
    gemv_pool_kernel<<<P, 256, 0, stream>>>(x, W, b, out, head, nextp);
}